// Round 5
// baseline (6304.287 us; speedup 1.0000x reference)
//
#include <hip/hip_runtime.h>

#define SS 512
#define II 1024
#define HH 1024
#define NELEM (32 * SS * II)   // B*S*I elements of x

typedef short bf16x8 __attribute__((ext_vector_type(8)));
typedef float f32x4 __attribute__((ext_vector_type(4)));
typedef unsigned int u32;
typedef u32 u32x4 __attribute__((ext_vector_type(4)));

__device__ __forceinline__ short f2bf_s(float f) {
    union { float fv; u32 i; } v; v.fv = f;
    u32 r = v.i + 0x7FFF + ((v.i >> 16) & 1);  // RNE
    return (short)(r >> 16);
}
__device__ __forceinline__ float sigm(float x)   { return 1.0f / (1.0f + __expf(-x)); }
__device__ __forceinline__ float tanh_f(float x) { return 2.0f / (1.0f + __expf(-2.0f * x)) - 1.0f; }

__device__ __forceinline__ bf16x8 cvt8(const float* p) {
    bf16x8 r;
#pragma unroll
    for (int j = 0; j < 8; ++j) r[j] = f2bf_s(p[j]);
    return r;
}

// Pre-pass: x f32 -> bf16 (exactly covers NELEM with 8192 x 256 x 8)
__global__ void __launch_bounds__(256)
cvt_x_kernel(const float* __restrict__ x, ushort* __restrict__ xb) {
    const int i = (blockIdx.x * 256 + threadIdx.x) * 8;
    *(bf16x8*)(xb + i) = cvt8(x + i);
}

#define A_ST(p, v) __hip_atomic_store((p), (v), __ATOMIC_RELAXED, __HIP_MEMORY_SCOPE_AGENT)

// Coherent (bypass L1/L2) 16B load — freshness validated via in-dword tags.
#define HLOADC(dst, base, OFF)                                             \
    asm volatile("global_load_dwordx4 %0, %1, off offset:" #OFF " sc0 sc1" \
                 : "=v"(dst) : "v"(base))
// Cached 16B load (x fragments; xb is read-shared by all blocks of a dir).
#define XLOAD(dst, base, OFF)                                \
    asm volatile("global_load_dwordx4 %0, %1, off offset:" #OFF \
                 : "=v"(dst) : "v"(base))
// Full drain + scheduler fence (rule #18). vmcnt(0) is robust against ANY
// compiler-inserted vmem (spills etc.) — counted waits (round 3/4) are NOT,
// and that under-drain is the prime suspect for round 4's wrong results.
#define VMWAIT0() do {                                          \
    asm volatile("s_waitcnt vmcnt(0)" ::: "memory");            \
    __builtin_amdgcn_sched_barrier(0);                          \
} while (0)

#define ISSUE_H() do {                                          \
    HLOADC(hA[0],  hbase0, 0);   HLOADC(hA[1],  hbase0, 16);    \
    HLOADC(hA[2],  hbase0, 128); HLOADC(hA[3],  hbase0, 144);   \
    HLOADC(hA[4],  hbase0, 256); HLOADC(hA[5],  hbase0, 272);   \
    HLOADC(hA[6],  hbase0, 384); HLOADC(hA[7],  hbase0, 400);   \
    HLOADC(hA[8],  hbase0, 512); HLOADC(hA[9],  hbase0, 528);   \
    HLOADC(hA[10], hbase0, 640); HLOADC(hA[11], hbase0, 656);   \
    HLOADC(hA[12], hbase0, 768); HLOADC(hA[13], hbase0, 784);   \
    HLOADC(hA[14], hbase0, 896); HLOADC(hA[15], hbase0, 912);   \
    HLOADC(hB[0],  hbase1, 0);   HLOADC(hB[1],  hbase1, 16);    \
    HLOADC(hB[2],  hbase1, 128); HLOADC(hB[3],  hbase1, 144);   \
    HLOADC(hB[4],  hbase1, 256); HLOADC(hB[5],  hbase1, 272);   \
    HLOADC(hB[6],  hbase1, 384); HLOADC(hB[7],  hbase1, 400);   \
    HLOADC(hB[8],  hbase1, 512); HLOADC(hB[9],  hbase1, 528);   \
    HLOADC(hB[10], hbase1, 640); HLOADC(hB[11], hbase1, 656);   \
    HLOADC(hB[12], hbase1, 768); HLOADC(hB[13], hbase1, 784);   \
    HLOADC(hB[14], hbase1, 896); HLOADC(hB[15], hbase1, 912);   \
} while (0)

#define TAGCHECK(diffv, expT) do {                              \
    diffv = 0;                                                  \
    _Pragma("unroll")                                           \
    for (int i_ = 0; i_ < 16; ++i_) {                           \
        _Pragma("unroll")                                       \
        for (int j_ = 0; j_ < 4; ++j_) {                        \
            diffv |= (hA[i_][j_] >> 16) ^ (expT);               \
            diffv |= (hB[i_][j_] >> 16) ^ (expT);               \
        }                                                       \
    }                                                           \
} while (0)

// Persistent BiLSTM, TAG-IN-DATA h exchange (no flags, no publish-ack).
// Grid 256x256. Block g: dir d=g>>7, owns 8 h-units. Weights bf16
// register-resident. h slab: 1 dword/unit = (tag=step+1)<<16 | bf16(h).
// Producer fire-and-forget stores; consumer bulk-loads tagged h + x at the
// step top, ONE vmcnt(0) (x L2-latency hides inside the h coherence RT),
// tag-checks once, overlaps the x-MFMAs with any producer-late retry RT.
// Protocol safety (as before): publish of tag t+1 is program-ordered after
// validating tag t from ALL producers, so slab overwrite (2 steps later)
// cannot precede any consumer's read; torn reads impossible (tag+data in
// one dword); stale tags differ by >=1 => retry. Bounded retry + backoff
// turns any residual protocol failure into a visible wrong-result.
// ROUND CHANGE vs failed round 4: ALL waits are vmcnt(0) — the counted
// vmcnt(34)/(16) pipeline could under-drain if the compiler emitted ANY
// vmem we didn't count (scratch spills at ~370 live VGPRs); that is the
// prime suspect for round 4's garbage. x prefetch pipeline dropped
// (was worth ~0.3us/step, carried all the accounting fragility).
template <int USE_XB>
__global__ void __launch_bounds__(256, 1)
bilstm_persist(const float* __restrict__ x,
               const float* __restrict__ Wii_f, const float* __restrict__ Whi_f,
               const float* __restrict__ bi_f,
               const float* __restrict__ Wii_r, const float* __restrict__ Whi_r,
               const float* __restrict__ bi_r,
               float* __restrict__ out, u32* __restrict__ hb,
               const ushort* __restrict__ xb)
{
    const int g   = blockIdx.x;
    const int d   = g >> 7;
    const int u0  = (g & 127) * 8;
    const int tid = threadIdx.x;
    const int w   = tid >> 6;
    const int l   = tid & 63;
    const int q   = l >> 4;
    const int ln  = l & 15;
    const int kw  = w * 256;

    const float* Wx = d ? Wii_r : Wii_f;
    const float* Wh = d ? Whi_r : Whi_f;
    const float* bi = d ? bi_r  : bi_f;

    // Weight fragments: B-frag lane holds B[k=q*8+j][n=ln] = W[col n][k]
    bf16x8 wx[8][2], wh[8][2];
#pragma unroll
    for (int nt = 0; nt < 2; ++nt) {
        const int n = nt * 16 + ln;                    // local gate-col 0..31
        const int r = (n >> 3) * HH + u0 + (n & 7);    // W row: gate*H + unit
#pragma unroll
        for (int it = 0; it < 8; ++it) {
            const int off = r * 1024 + kw + it * 32 + q * 8;
            wx[it][nt] = cvt8(Wx + off);
            wh[it][nt] = cvt8(Wh + off);
        }
    }

    const int eb = tid >> 3;   // batch 0..31
    const int eu = tid & 7;    // local unit 0..7
    float bias[4];
#pragma unroll
    for (int gate = 0; gate < 4; ++gate)
        bias[gate] = bi[gate * HH + u0 + eu];

    float c_state = 0.0f;
    __shared__ float part[2][4][32][33];   // double-buffered by t&1
    const f32x4 zero4 = {0.0f, 0.0f, 0.0f, 0.0f};

    u32x4 xr0[8], xr1[8];   // x fragments for the current step
    u32x4 hA[16], hB[16];   // tagged h (rows ln / ln+16)

    for (int t = 0; t < SS; ++t) {
        const int tx = d ? (SS - 1 - t) : t;
        // slabs: slot*2+d, 32 rows x 1024 dwords (1 dword per unit)
        const u32* hrd = hb + (size_t)(((t & 1) ^ 1) * 2 + d) * 32 * 1024;
        u32*       hwp = hb + (size_t)((t & 1) * 2 + d) * 32 * 1024;

        const u32* hbase0 = hrd + ln * 1024 + kw + q * 8;
        const u32* hbase1 = hbase0 + 16 * 1024;

        f32x4 acc[2][2];
        acc[0][0] = zero4; acc[0][1] = zero4; acc[1][0] = zero4; acc[1][1] = zero4;

        // issue tagged-h bulk load, then x loads: x L2 latency hides inside
        // the h coherence-point round trip; one drain covers both
        if (t > 0) ISSUE_H();
        if (USE_XB) {
            const ushort* b0 = xb + ((size_t)(ln * SS + tx)) * II + kw + q * 8;
            const ushort* b1 = xb + ((size_t)((16 + ln) * SS + tx)) * II + kw + q * 8;
            XLOAD(xr0[0], b0, 0);   XLOAD(xr0[1], b0, 64);
            XLOAD(xr0[2], b0, 128); XLOAD(xr0[3], b0, 192);
            XLOAD(xr0[4], b0, 256); XLOAD(xr0[5], b0, 320);
            XLOAD(xr0[6], b0, 384); XLOAD(xr0[7], b0, 448);
            XLOAD(xr1[0], b1, 0);   XLOAD(xr1[1], b1, 64);
            XLOAD(xr1[2], b1, 128); XLOAD(xr1[3], b1, 192);
            XLOAD(xr1[4], b1, 256); XLOAD(xr1[5], b1, 320);
            XLOAD(xr1[6], b1, 384); XLOAD(xr1[7], b1, 448);
            VMWAIT0();
        }

        // first tag check BEFORE the x-MFMAs: if producers are late, the
        // retry round trip overlaps the x compute below
        u32 diffv = 0;
        if (t > 0) TAGCHECK(diffv, (u32)t);

        // ---- x part ----
        if (USE_XB) {
#pragma unroll
            for (int it = 0; it < 8; ++it) {
                const bf16x8 ax0 = __builtin_bit_cast(bf16x8, xr0[it]);
                const bf16x8 ax1 = __builtin_bit_cast(bf16x8, xr1[it]);
                acc[0][0] = __builtin_amdgcn_mfma_f32_16x16x32_bf16(ax0, wx[it][0], acc[0][0], 0, 0, 0);
                acc[0][1] = __builtin_amdgcn_mfma_f32_16x16x32_bf16(ax0, wx[it][1], acc[0][1], 0, 0, 0);
                acc[1][0] = __builtin_amdgcn_mfma_f32_16x16x32_bf16(ax1, wx[it][0], acc[1][0], 0, 0, 0);
                acc[1][1] = __builtin_amdgcn_mfma_f32_16x16x32_bf16(ax1, wx[it][1], acc[1][1], 0, 0, 0);
            }
        } else {
            if (t > 0) VMWAIT0();   // fallback: ensure h regs ready too
#pragma unroll
            for (int it = 0; it < 8; ++it) {
                const int ko = kw + it * 32 + q * 8;
                const bf16x8 ax0 = cvt8(x + ((size_t)(ln * SS + tx)) * II + ko);
                const bf16x8 ax1 = cvt8(x + ((size_t)((16 + ln) * SS + tx)) * II + ko);
                acc[0][0] = __builtin_amdgcn_mfma_f32_16x16x32_bf16(ax0, wx[it][0], acc[0][0], 0, 0, 0);
                acc[0][1] = __builtin_amdgcn_mfma_f32_16x16x32_bf16(ax0, wx[it][1], acc[0][1], 0, 0, 0);
                acc[1][0] = __builtin_amdgcn_mfma_f32_16x16x32_bf16(ax1, wx[it][0], acc[1][0], 0, 0, 0);
                acc[1][1] = __builtin_amdgcn_mfma_f32_16x16x32_bf16(ax1, wx[it][1], acc[1][1], 0, 0, 0);
            }
        }

        // ---- h part: retry (rare) then MFMA ----
        if (t > 0) {
            // bounded retry with backoff: legit skew needs a few passes;
            // 4096 (~8ms) exhaustion => visible wrong result, not a hang
            for (int tries = 0; tries < 4096 && !__all(diffv == 0); ++tries) {
                __builtin_amdgcn_s_sleep(4);
                ISSUE_H();
                VMWAIT0();
                TAGCHECK(diffv, (u32)t);
            }
            // extract bf16 pairs and run h-MFMAs
#pragma unroll
            for (int it = 0; it < 8; ++it) {
                u32x4 fa, fb;
                fa[0] = (hA[2*it][0]   & 0xffffu) | (hA[2*it][1]   << 16);
                fa[1] = (hA[2*it][2]   & 0xffffu) | (hA[2*it][3]   << 16);
                fa[2] = (hA[2*it+1][0] & 0xffffu) | (hA[2*it+1][1] << 16);
                fa[3] = (hA[2*it+1][2] & 0xffffu) | (hA[2*it+1][3] << 16);
                fb[0] = (hB[2*it][0]   & 0xffffu) | (hB[2*it][1]   << 16);
                fb[1] = (hB[2*it][2]   & 0xffffu) | (hB[2*it][3]   << 16);
                fb[2] = (hB[2*it+1][0] & 0xffffu) | (hB[2*it+1][1] << 16);
                fb[3] = (hB[2*it+1][2] & 0xffffu) | (hB[2*it+1][3] << 16);
                const bf16x8 ah0 = __builtin_bit_cast(bf16x8, fa);
                const bf16x8 ah1 = __builtin_bit_cast(bf16x8, fb);
                acc[0][0] = __builtin_amdgcn_mfma_f32_16x16x32_bf16(ah0, wh[it][0], acc[0][0], 0, 0, 0);
                acc[0][1] = __builtin_amdgcn_mfma_f32_16x16x32_bf16(ah0, wh[it][1], acc[0][1], 0, 0, 0);
                acc[1][0] = __builtin_amdgcn_mfma_f32_16x16x32_bf16(ah1, wh[it][0], acc[1][0], 0, 0, 0);
                acc[1][1] = __builtin_amdgcn_mfma_f32_16x16x32_bf16(ah1, wh[it][1], acc[1][1], 0, 0, 0);
            }
        }

        // C/D: reg r of lane = D[m=q*4+r][n=ln]; double-buffered by t&1
        // (one barrier per step suffices: writes at t+2 into this buffer
        // are ordered after ALL waves' reads at t via the t+1 barrier)
        {
            float (*pb)[32][33] = part[t & 1];
#pragma unroll
            for (int mt = 0; mt < 2; ++mt)
#pragma unroll
                for (int nt = 0; nt < 2; ++nt)
#pragma unroll
                    for (int r4 = 0; r4 < 4; ++r4)
                        pb[w][mt * 16 + q * 4 + r4][nt * 16 + ln] = acc[mt][nt][r4];
        }
        // fenced raw barrier (NOT __syncthreads: don't drain in-flight
        // stores). LDS writes drained (lgkmcnt) + code motion fenced.
        asm volatile("s_waitcnt lgkmcnt(0)" ::: "memory");
        __builtin_amdgcn_s_barrier();
        __builtin_amdgcn_sched_barrier(0);
        asm volatile("" ::: "memory");

        float gi[4];
        {
            float (*pb)[32][33] = part[t & 1];
#pragma unroll
            for (int gate = 0; gate < 4; ++gate) {
                float s = bias[gate];
#pragma unroll
                for (int w2 = 0; w2 < 4; ++w2) s += pb[w2][eb][gate * 8 + eu];
                gi[gate] = s;
            }
        }
        const float igate = sigm(gi[0]);
        const float fgate = sigm(gi[1]);
        const float ggate = tanh_f(gi[2]);
        const float ogate = sigm(gi[3]);
        c_state = fgate * c_state + igate * ggate;
        const float hv = ogate * tanh_f(c_state);

        // fire-and-forget tagged publish (no ack wait, no flag)
        const u32 tagv = ((u32)(t + 1) << 16) | (u32)(unsigned short)f2bf_s(hv);
        A_ST(hwp + eb * 1024 + u0 + eu, tagv);
        out[((size_t)(eb * SS + tx)) * (2 * HH) + d * HH + u0 + eu] = hv;
    }
}

extern "C" void kernel_launch(void* const* d_in, const int* in_sizes, int n_in,
                              void* d_out, int out_size, void* d_ws, size_t ws_size,
                              hipStream_t stream)
{
    const float* x    = (const float*)d_in[0];
    const float* Wii  = (const float*)d_in[1];
    const float* Whi  = (const float*)d_in[2];
    const float* bi   = (const float*)d_in[3];
    const float* WiiR = (const float*)d_in[4];
    const float* WhiR = (const float*)d_in[5];
    const float* biR  = (const float*)d_in[6];
    float* out = (float*)d_out;

    // ws: [0,512K) tagged h ping-pong (2 slots x 2 dir x 32 b x 1024 dwords)
    //     [1M, 1M+32M) bf16 x copy
    u32* hb    = (u32*)d_ws;
    ushort* xb = (ushort*)((char*)d_ws + 1024 * 1024);
    const int use_xb = (ws_size >= 1024 * 1024 + (size_t)NELEM * 2) ? 1 : 0;

    hipMemsetAsync(d_ws, 0, 512 * 1024, stream);   // zero tags each launch

    if (use_xb) {
        hipLaunchKernelGGL(cvt_x_kernel, dim3(NELEM / (256 * 8)), dim3(256), 0, stream, x, xb);
        hipLaunchKernelGGL((bilstm_persist<1>), dim3(256), dim3(256), 0, stream,
                           x, Wii, Whi, bi, WiiR, WhiR, biR, out, hb, xb);
    } else {
        hipLaunchKernelGGL((bilstm_persist<0>), dim3(256), dim3(256), 0, stream,
                           x, Wii, Whi, bi, WiiR, WhiR, biR, out, hb, xb);
    }
}